// Round 1
// baseline (500.943 us; speedup 1.0000x reference)
//
#include <hip/hip_runtime.h>
#include <hip/hip_bf16.h>
#include <stdint.h>

// Problem dims (fixed by the reference setup)
#define BDIM 8192      // rows of x
#define CDIM 10000     // class means
#define CPAD 10112     // 79 * 128
#define FDIM 2048      // feature dim (K)

#define BM 128
#define BN 128
#define BK 64

typedef __attribute__((ext_vector_type(8))) __bf16 bf16x8;
typedef __attribute__((ext_vector_type(4))) float  f32x4;

// ---------------------------------------------------------------------------
// Prep: f32 rows -> bf16 rows (RNE), plus per-row sum of squares in f32.
// One block (256 threads) per output row; rows >= nvalid are zero-padded.
// ---------------------------------------------------------------------------
__global__ __launch_bounds__(256) void convert_rows(
    const float* __restrict__ src, unsigned short* __restrict__ dst,
    float* __restrict__ sq, int nvalid)
{
    const int row = blockIdx.x;
    const int tid = threadIdx.x;
    unsigned short* drow = dst + (size_t)row * FDIM;

    if (row >= nvalid) {
        uint4 z = make_uint4(0, 0, 0, 0);
        ((uint4*)drow)[tid] = z;
        if (tid == 0) sq[row] = 0.0f;
        return;
    }

    const float4* s = (const float4*)(src + (size_t)row * FDIM);
    float4 v0 = s[tid * 2 + 0];
    float4 v1 = s[tid * 2 + 1];

    float f[8] = {v0.x, v0.y, v0.z, v0.w, v1.x, v1.y, v1.z, v1.w};
    float ssum = 0.0f;
    union { unsigned short u[8]; uint4 v; } pk;
#pragma unroll
    for (int j = 0; j < 8; ++j) {
        ssum += f[j] * f[j];
        uint32_t b = __builtin_bit_cast(uint32_t, f[j]);
        // round-to-nearest-even bf16 (inputs are finite)
        b = b + 0x7fffu + ((b >> 16) & 1u);
        pk.u[j] = (unsigned short)(b >> 16);
    }
    ((uint4*)drow)[tid] = pk.v;

    // wave reduce (64 lanes) then cross-wave via LDS
#pragma unroll
    for (int off = 32; off > 0; off >>= 1)
        ssum += __shfl_down(ssum, off, 64);
    __shared__ float red[4];
    if ((tid & 63) == 0) red[tid >> 6] = ssum;
    __syncthreads();
    if (tid == 0) sq[row] = red[0] + red[1] + red[2] + red[3];
}

// ---------------------------------------------------------------------------
// bf16 GEMM (both operands K-major) with fused -dist^2 epilogue.
// C[i][j] = 2*sum_k X[i][k]*M[j][k] - xsq[i] - msq[j]
// m97 structure: 128x128 tile, BK=64, 4 waves (2x2 of 64x64 each),
// global_load_lds width-16 staging, ds_read_b128 fragments, 16x16x32 MFMA.
// ---------------------------------------------------------------------------
__global__ __launch_bounds__(256, 2) void nscm_gemm(
    const unsigned short* __restrict__ Xb, const unsigned short* __restrict__ Mb,
    const float* __restrict__ xsq, const float* __restrict__ msq,
    float* __restrict__ out)
{
    __shared__ unsigned short As[BM * BK];
    __shared__ unsigned short Bs[BN * BK];

    const int tile_n = blockIdx.x;   // 0..78
    const int tile_m = blockIdx.y;   // 0..63
    const int tid  = threadIdx.x;
    const int lane = tid & 63;
    const int wave = tid >> 6;       // 0..3
    const int wr = wave >> 1;        // 0..1
    const int wc = wave & 1;         // 0..1

    const int row0 = tile_m * BM;
    const int col0 = tile_n * BN;

    // staging geometry: chunk = wave*4+i covers rows [chunk*8, chunk*8+8)
    const int srow = lane >> 3;            // 0..7 within chunk
    const int scol = (lane & 7) * 8;       // bf16 col, 8 elems = 16B

    f32x4 acc[4][4] = {};

    for (int k0 = 0; k0 < FDIM; k0 += BK) {
#pragma unroll
        for (int i = 0; i < 4; ++i) {
            const int chunk = wave * 4 + i;
            const int r = chunk * 8 + srow;
            const unsigned short* ga = Xb + (size_t)(row0 + r) * FDIM + k0 + scol;
            __builtin_amdgcn_global_load_lds(
                (const __attribute__((address_space(1))) void*)ga,
                (__attribute__((address_space(3))) void*)&As[chunk * 8 * BK],
                16, 0, 0);
            const unsigned short* gb = Mb + (size_t)(col0 + r) * FDIM + k0 + scol;
            __builtin_amdgcn_global_load_lds(
                (const __attribute__((address_space(1))) void*)gb,
                (__attribute__((address_space(3))) void*)&Bs[chunk * 8 * BK],
                16, 0, 0);
        }
        asm volatile("s_waitcnt vmcnt(0)" ::: "memory");
        __syncthreads();

#pragma unroll
        for (int kk = 0; kk < 2; ++kk) {
            const int kb = kk * 32 + (lane >> 4) * 8;
            bf16x8 av[4], bv[4];
#pragma unroll
            for (int fm = 0; fm < 4; ++fm)
                av[fm] = *(const bf16x8*)&As[(wr * 64 + fm * 16 + (lane & 15)) * BK + kb];
#pragma unroll
            for (int fn = 0; fn < 4; ++fn)
                bv[fn] = *(const bf16x8*)&Bs[(wc * 64 + fn * 16 + (lane & 15)) * BK + kb];
#pragma unroll
            for (int fm = 0; fm < 4; ++fm)
#pragma unroll
                for (int fn = 0; fn < 4; ++fn)
                    acc[fm][fn] = __builtin_amdgcn_mfma_f32_16x16x32_bf16(
                        av[fm], bv[fn], acc[fm][fn], 0, 0, 0);
        }
        __syncthreads();
    }

    // epilogue: out[i][j] = 2*acc - xsq[i] - msq[j]
    const int lrow = (lane >> 4) * 4;
    const int lcol = lane & 15;
#pragma unroll
    for (int fm = 0; fm < 4; ++fm) {
        const int i0 = row0 + wr * 64 + fm * 16 + lrow;
        float xs[4];
#pragma unroll
        for (int r = 0; r < 4; ++r) xs[r] = xsq[i0 + r];
#pragma unroll
        for (int fn = 0; fn < 4; ++fn) {
            const int j = col0 + wc * 64 + fn * 16 + lcol;
            if (j < CDIM) {
                const float ms = msq[j];
#pragma unroll
                for (int r = 0; r < 4; ++r)
                    out[(size_t)(i0 + r) * CDIM + j] =
                        2.0f * acc[fm][fn][r] - xs[r] - ms;
            }
        }
    }
}

// ---------------------------------------------------------------------------
extern "C" void kernel_launch(void* const* d_in, const int* in_sizes, int n_in,
                              void* d_out, int out_size, void* d_ws, size_t ws_size,
                              hipStream_t stream) {
    const float* x     = (const float*)d_in[0];   // [8192, 2048]
    const float* means = (const float*)d_in[1];   // [10000, 2048]
    float* out = (float*)d_out;                   // [8192, 10000]

    char* ws = (char*)d_ws;
    unsigned short* Xb = (unsigned short*)ws;                            // 8192*2048 bf16
    unsigned short* Mb = (unsigned short*)(ws + (size_t)BDIM * FDIM * 2);// 10112*2048 bf16
    float* xsq = (float*)(ws + (size_t)BDIM * FDIM * 2 + (size_t)CPAD * FDIM * 2);
    float* msq = xsq + BDIM;

    convert_rows<<<BDIM, 256, 0, stream>>>(x, Xb, xsq, BDIM);
    convert_rows<<<CPAD, 256, 0, stream>>>(means, Mb, msq, CDIM);

    dim3 grid(CPAD / BN, BDIM / BM);   // (79, 64)
    nscm_gemm<<<grid, 256, 0, stream>>>(Xb, Mb, xsq, msq, out);
}

// Round 2
// 402.434 us; speedup vs baseline: 1.2448x; 1.2448x over previous
//
#include <hip/hip_runtime.h>
#include <hip/hip_bf16.h>
#include <stdint.h>

// Problem dims (fixed by the reference setup)
#define BDIM 8192      // rows of x
#define CDIM 10000     // class means
#define CPAD 10240     // 40 * 256
#define FDIM 2048      // feature dim (K)

#define BM 256
#define BN 256
#define BK 64
#define NT (FDIM / BK)          // 32 K-tiles
#define TM (BDIM / BM)          // 32
#define TN (CPAD / BN)          // 40
#define NWG (TM * TN)           // 1280, multiple of 8

#define LDS_BUF_ELEMS 32768     // (BM*BK + BN*BK) bf16 elems = 64 KB
#define LDS_BYTES 131072        // 2 buffers = 128 KB

typedef __attribute__((ext_vector_type(8))) __bf16 bf16x8;
typedef __attribute__((ext_vector_type(4))) float  f32x4;

#define AS1 __attribute__((address_space(1)))
#define AS3 __attribute__((address_space(3)))

// ---------------------------------------------------------------------------
// Prep: f32 rows -> bf16 rows (RNE), plus per-row sum of squares in f32.
// One block (256 threads) per output row; rows >= nvalid are zero-padded.
// ---------------------------------------------------------------------------
__global__ __launch_bounds__(256) void convert_rows(
    const float* __restrict__ src, unsigned short* __restrict__ dst,
    float* __restrict__ sq, int nvalid)
{
    const int row = blockIdx.x;
    const int tid = threadIdx.x;
    unsigned short* drow = dst + (size_t)row * FDIM;

    if (row >= nvalid) {
        uint4 z = make_uint4(0, 0, 0, 0);
        ((uint4*)drow)[tid] = z;
        if (tid == 0) sq[row] = 0.0f;
        return;
    }

    const float4* s = (const float4*)(src + (size_t)row * FDIM);
    float4 v0 = s[tid * 2 + 0];
    float4 v1 = s[tid * 2 + 1];

    float f[8] = {v0.x, v0.y, v0.z, v0.w, v1.x, v1.y, v1.z, v1.w};
    float ssum = 0.0f;
    union { unsigned short u[8]; uint4 v; } pk;
#pragma unroll
    for (int j = 0; j < 8; ++j) {
        ssum += f[j] * f[j];
        uint32_t b = __builtin_bit_cast(uint32_t, f[j]);
        b = b + 0x7fffu + ((b >> 16) & 1u);   // RNE to bf16
        pk.u[j] = (unsigned short)(b >> 16);
    }
    ((uint4*)drow)[tid] = pk.v;

#pragma unroll
    for (int off = 32; off > 0; off >>= 1)
        ssum += __shfl_down(ssum, off, 64);
    __shared__ float red[4];
    if ((tid & 63) == 0) red[tid >> 6] = ssum;
    __syncthreads();
    if (tid == 0) sq[row] = red[0] + red[1] + red[2] + red[3];
}

// ---------------------------------------------------------------------------
// 256x256 bf16 GEMM, counted-vmcnt pipeline (T1+T2+T4+T5), fused epilogue:
// out[i][j] = 2*sum_k X[i][k]*M[j][k] - xsq[i] - msq[j]
//
// 8 waves (2M x 4N), per-wave 128x64 output, BK=64, double-buffered LDS
// (128 KB), global_load_lds width-16 staging with pre-swizzled source
// columns (rule #21), XOR-swizzled ds_read_b128 (T2), raw s_barrier +
// s_waitcnt vmcnt(8) so 8 prefetch loads stay in flight across barriers (T4).
// ---------------------------------------------------------------------------
__global__ __launch_bounds__(512, 2) void nscm_gemm(
    const unsigned short* __restrict__ Xb, const unsigned short* __restrict__ Mb,
    const float* __restrict__ xsq, const float* __restrict__ msq,
    float* __restrict__ out)
{
    extern __shared__ unsigned short lds[];

    const int tid  = threadIdx.x;
    const int lane = tid & 63;
    const int wave = tid >> 6;       // 0..7
    const int wr = wave >> 2;        // 0..1  (M half)
    const int wc = wave & 3;         // 0..3  (N quarter)
    const int fr = lane & 15;        // fragment row/col within 16
    const int kq = lane >> 4;        // 0..3  (k quarter)

    // T1: bijective XCD swizzle (NWG % 8 == 0)
    const int bid = blockIdx.x;
    const int swz = (bid & 7) * (NWG / 8) + (bid >> 3);
    const int tile_m = swz / TN;
    const int tile_n = swz % TN;
    const int row0 = tile_m * BM;
    const int col0 = tile_n * BN;

    // staging geometry: per issue l, rows l*64 + (tid>>3); lane col (tid&7)*8
    // source col pre-swizzled so linear LDS dest + swizzled read match (rule 21)
    const int srow = tid >> 3;                       // 0..63
    const int sce  = ((tid & 7) ^ (srow & 7)) * 8;   // swizzled bf16 col

    f32x4 acc[8][4] = {};

    // stage K-tile t into buffer buf (8 global_load_lds per thread)
    auto stage = [&](int t, int buf) {
        const int k0 = t * BK;
        unsigned short* Ab = lds + buf * LDS_BUF_ELEMS;
        unsigned short* Bb = Ab + BM * BK;
#pragma unroll
        for (int l = 0; l < 4; ++l) {
            const int r = l * 64 + srow;
            const unsigned short* ga = Xb + (size_t)(row0 + r) * FDIM + k0 + sce;
            __builtin_amdgcn_global_load_lds(
                (const AS1 void*)ga,
                (AS3 void*)(Ab + (l * 64 + wave * 8) * BK), 16, 0, 0);
            const unsigned short* gb = Mb + (size_t)(col0 + r) * FDIM + k0 + sce;
            __builtin_amdgcn_global_load_lds(
                (const AS1 void*)gb,
                (AS3 void*)(Bb + (l * 64 + wave * 8) * BK), 16, 0, 0);
        }
    };

    // prologue: tile 0 resident
    stage(0, 0);
    asm volatile("s_waitcnt vmcnt(0)\n\ts_barrier" ::: "memory");

    const int xorv = (fr & 7) << 4;  // T2 read-side XOR (row&7 == fr&7)

    for (int t = 0; t < NT; ++t) {
        // issue next tile's loads, then retire tile t's (keep 8 in flight: T4)
        if (t + 1 < NT) {
            stage(t + 1, (t + 1) & 1);
            asm volatile("s_waitcnt vmcnt(8)\n\ts_barrier" ::: "memory");
        } else {
            asm volatile("s_waitcnt vmcnt(0)\n\ts_barrier" ::: "memory");
        }

        const unsigned short* Ab = lds + (t & 1) * LDS_BUF_ELEMS;
        const unsigned short* Bb = Ab + BM * BK;

#pragma unroll
        for (int ks = 0; ks < 2; ++ks) {
            const int cbx = (ks * 64 + kq * 16) ^ xorv;
            bf16x8 av[8], bv[4];
#pragma unroll
            for (int fm = 0; fm < 8; ++fm) {
                const int row = wr * 128 + fm * 16 + fr;
                av[fm] = *(const bf16x8*)((const char*)Ab + row * 128 + cbx);
            }
#pragma unroll
            for (int fn = 0; fn < 4; ++fn) {
                const int row = wc * 64 + fn * 16 + fr;
                bv[fn] = *(const bf16x8*)((const char*)Bb + row * 128 + cbx);
            }
            __builtin_amdgcn_s_setprio(1);
#pragma unroll
            for (int fm = 0; fm < 8; ++fm)
#pragma unroll
                for (int fn = 0; fn < 4; ++fn)
                    acc[fm][fn] = __builtin_amdgcn_mfma_f32_16x16x32_bf16(
                        av[fm], bv[fn], acc[fm][fn], 0, 0, 0);
            __builtin_amdgcn_s_setprio(0);
        }

        // all waves' reads of buf (t&1) done before next iter overwrites it
        asm volatile("s_waitcnt lgkmcnt(0)\n\ts_barrier" ::: "memory");
        __builtin_amdgcn_sched_barrier(0);
    }

    // epilogue: out[i][j] = 2*acc - xsq[i] - msq[j]
#pragma unroll
    for (int fm = 0; fm < 8; ++fm) {
        const int i0 = row0 + wr * 128 + fm * 16 + kq * 4;
        float xs[4];
#pragma unroll
        for (int r = 0; r < 4; ++r) xs[r] = xsq[i0 + r];
#pragma unroll
        for (int fn = 0; fn < 4; ++fn) {
            const int j = col0 + wc * 64 + fn * 16 + fr;
            if (j < CDIM) {
                const float ms = msq[j];
#pragma unroll
                for (int r = 0; r < 4; ++r)
                    out[(size_t)(i0 + r) * CDIM + j] =
                        2.0f * acc[fm][fn][r] - xs[r] - ms;
            }
        }
    }
}

// ---------------------------------------------------------------------------
extern "C" void kernel_launch(void* const* d_in, const int* in_sizes, int n_in,
                              void* d_out, int out_size, void* d_ws, size_t ws_size,
                              hipStream_t stream) {
    const float* x     = (const float*)d_in[0];   // [8192, 2048]
    const float* means = (const float*)d_in[1];   // [10000, 2048]
    float* out = (float*)d_out;                   // [8192, 10000]

    char* ws = (char*)d_ws;
    unsigned short* Xb = (unsigned short*)ws;                             // 8192*2048 bf16
    unsigned short* Mb = (unsigned short*)(ws + (size_t)BDIM * FDIM * 2); // 10240*2048 bf16
    float* xsq = (float*)(ws + (size_t)BDIM * FDIM * 2 + (size_t)CPAD * FDIM * 2);
    float* msq = xsq + BDIM;

    // allow 128 KB dynamic LDS (ignore error if already set / not needed)
    (void)hipFuncSetAttribute((const void*)nscm_gemm,
                              hipFuncAttributeMaxDynamicSharedMemorySize,
                              LDS_BYTES);

    convert_rows<<<BDIM, 256, 0, stream>>>(x, Xb, xsq, BDIM);
    convert_rows<<<CPAD, 256, 0, stream>>>(means, Mb, msq, CDIM);

    nscm_gemm<<<NWG, 512, LDS_BYTES, stream>>>(Xb, Mb, xsq, msq, out);
}

// Round 3
// 381.502 us; speedup vs baseline: 1.3131x; 1.0549x over previous
//
#include <hip/hip_runtime.h>
#include <hip/hip_bf16.h>
#include <stdint.h>

// Problem dims (fixed by the reference setup)
#define BDIM 8192      // rows of x
#define CDIM 10000     // class means
#define CPAD 10240     // 40 * 256
#define FDIM 2048      // feature dim (K)

#define BM 256
#define BN 256
#define BK 64
#define NT (FDIM / BK)          // 32 K-tiles
#define NI (NT / 2)             // 16 iterations (2 K-tiles each)
#define TM (BDIM / BM)          // 32
#define TN (CPAD / BN)          // 40
#define NWG (TM * TN)           // 1280, multiple of 8

#define HT_BYTES   16384        // one half-tile region (128 rows x 128 B)
#define DBUF_BYTES 65536        // A0|A1|B0|B1
#define LDS_BYTES  131072       // 2 dbuf slots

typedef __attribute__((ext_vector_type(8))) __bf16 bf16x8;
typedef __attribute__((ext_vector_type(4))) float  f32x4;

#define AS1 __attribute__((address_space(1)))
#define AS3 __attribute__((address_space(3)))

// ---------------------------------------------------------------------------
// Prep: f32 rows -> bf16 rows (RNE), plus per-row sum of squares in f32.
// ---------------------------------------------------------------------------
__global__ __launch_bounds__(256) void convert_rows(
    const float* __restrict__ src, unsigned short* __restrict__ dst,
    float* __restrict__ sq, int nvalid)
{
    const int row = blockIdx.x;
    const int tid = threadIdx.x;
    unsigned short* drow = dst + (size_t)row * FDIM;

    if (row >= nvalid) {
        uint4 z = make_uint4(0, 0, 0, 0);
        ((uint4*)drow)[tid] = z;
        if (tid == 0) sq[row] = 0.0f;
        return;
    }

    const float4* s = (const float4*)(src + (size_t)row * FDIM);
    float4 v0 = s[tid * 2 + 0];
    float4 v1 = s[tid * 2 + 1];

    float f[8] = {v0.x, v0.y, v0.z, v0.w, v1.x, v1.y, v1.z, v1.w};
    float ssum = 0.0f;
    union { unsigned short u[8]; uint4 v; } pk;
#pragma unroll
    for (int j = 0; j < 8; ++j) {
        ssum += f[j] * f[j];
        uint32_t b = __builtin_bit_cast(uint32_t, f[j]);
        b = b + 0x7fffu + ((b >> 16) & 1u);   // RNE to bf16
        pk.u[j] = (unsigned short)(b >> 16);
    }
    ((uint4*)drow)[tid] = pk.v;

#pragma unroll
    for (int off = 32; off > 0; off >>= 1)
        ssum += __shfl_down(ssum, off, 64);
    __shared__ float red[4];
    if ((tid & 63) == 0) red[tid >> 6] = ssum;
    __syncthreads();
    if (tid == 0) sq[row] = red[0] + red[1] + red[2] + red[3];
}

// ---------------------------------------------------------------------------
// 256x256 bf16 GEMM, 8-phase counted-vmcnt schedule (T1+T2+T3+T4+T5),
// fused epilogue: out[i][j] = 2*sum_k X[i][k]*M[j][k] - xsq[i] - msq[j]
//
// 8 waves (2M x 4N), per-wave 128x64 output. Each iteration covers 2 K-tiles
// (even->buf0, odd->buf1), 4 quadrant-phases each. Half-tile regions:
//   Ah(h) = A rows with bit6==h  (what quadrant mh=h reads, across waves)
//   Bh(h) = B rows with bit5==h  (what quadrant nh=h reads)
// Each phase: ds_read one register subtile + stage exactly 1 half-tile,
// barrier, lgkmcnt(0), setprio(1), 16 MFMA, setprio(0), barrier.
// vmcnt(6) only at phases 4 and 8 (3 half-tiles stay in flight).
// ---------------------------------------------------------------------------
#define MIDSYNC() do { \
    __builtin_amdgcn_s_barrier(); \
    asm volatile("s_waitcnt lgkmcnt(0)" ::: "memory"); \
    __builtin_amdgcn_sched_barrier(0); \
} while (0)

#define ENDBAR() do { \
    __builtin_amdgcn_s_barrier(); \
    __builtin_amdgcn_sched_barrier(0); \
} while (0)

#define QUAD(MH, BV, NH) do { \
    __builtin_amdgcn_s_setprio(1); \
    _Pragma("unroll") \
    for (int f = 0; f < 4; ++f) \
      _Pragma("unroll") \
      for (int f2 = 0; f2 < 2; ++f2) \
        _Pragma("unroll") \
        for (int ks = 0; ks < 2; ++ks) \
          acc[(MH)*4+f][(NH)*2+f2] = __builtin_amdgcn_mfma_f32_16x16x32_bf16( \
              av[f][ks], BV[f2][ks], acc[(MH)*4+f][(NH)*2+f2], 0, 0, 0); \
    __builtin_amdgcn_s_setprio(0); \
} while (0)

__global__ __launch_bounds__(512, 2) void nscm_gemm(
    const unsigned short* __restrict__ Xb, const unsigned short* __restrict__ Mb,
    const float* __restrict__ xsq, const float* __restrict__ msq,
    float* __restrict__ out)
{
    extern __shared__ char lds[];

    const int tid  = threadIdx.x;
    const int lane = tid & 63;
    const int wave = tid >> 6;       // 0..7
    const int wr = wave >> 2;        // 0..1  (M half)
    const int wc = wave & 3;         // 0..3  (N quarter)
    const int fr = lane & 15;
    const int kq = lane >> 4;        // 0..3

    // T1: bijective XCD swizzle (NWG % 8 == 0)
    const int bid = blockIdx.x;
    const int swz = (bid & 7) * (NWG / 8) + (bid >> 3);
    const int tile_m = swz / TN;
    const int tile_n = swz % TN;
    const int row0 = tile_m * BM;
    const int col0 = tile_n * BN;

    const int w8  = tid >> 3;                          // wave*8 + lane>>3
    const int sce = ((tid & 7) ^ (w8 & 7)) * 8;        // pre-swizzled src col (elems)
    const int xorv = (fr & 7) << 4;                    // T2 read-side XOR

    f32x4 acc[8][4] = {};
    bf16x8 av[4][2], bv0[2][2], bv1[2][2];

    // stage one A half-tile (h: rows with bit6==h) of K-tile kt into buf
    auto stageA = [&](int kt, int buf, int h) {
#pragma unroll
        for (int l = 0; l < 2; ++l) {
            const int w = l * 64 + w8;                           // 0..127 in-half
            const int grow = row0 + (w >> 6) * 128 + h * 64 + (w & 63);
            const unsigned short* src = Xb + (size_t)grow * FDIM + kt * BK + sce;
            char* dst = lds + buf * DBUF_BYTES + h * HT_BYTES
                        + (l * 64 + wave * 8) * 128;
            __builtin_amdgcn_global_load_lds((const AS1 void*)src,
                                             (AS3 void*)dst, 16, 0, 0);
        }
    };
    // stage one B half-tile (h: rows with bit5==h)
    auto stageB = [&](int kt, int buf, int h) {
#pragma unroll
        for (int l = 0; l < 2; ++l) {
            const int w = l * 64 + w8;
            const int grow = col0 + (w >> 5) * 64 + h * 32 + (w & 31);
            const unsigned short* src = Mb + (size_t)grow * FDIM + kt * BK + sce;
            char* dst = lds + buf * DBUF_BYTES + 32768 + h * HT_BYTES
                        + (l * 64 + wave * 8) * 128;
            __builtin_amdgcn_global_load_lds((const AS1 void*)src,
                                             (AS3 void*)dst, 16, 0, 0);
        }
    };

    auto loadA = [&](int buf, int mh) {
        const char* base = lds + buf * DBUF_BYTES + mh * HT_BYTES;
#pragma unroll
        for (int f = 0; f < 4; ++f) {
            const int w = wr * 64 + f * 16 + fr;
#pragma unroll
            for (int ks = 0; ks < 2; ++ks)
                av[f][ks] = *(const bf16x8*)(base + w * 128 +
                                             ((ks * 64 + kq * 16) ^ xorv));
        }
    };
    auto loadB = [&](int buf, int nh, bf16x8 (&bv)[2][2]) {
        const char* base = lds + buf * DBUF_BYTES + 32768 + nh * HT_BYTES;
#pragma unroll
        for (int f = 0; f < 2; ++f) {
            const int w = wc * 32 + f * 16 + fr;
#pragma unroll
            for (int ks = 0; ks < 2; ++ks)
                bv[f][ks] = *(const bf16x8*)(base + w * 128 +
                                             ((ks * 64 + kq * 16) ^ xorv));
        }
    };

    // prologue: 7 half-tiles (buf0 tile0 complete + 3/4 of buf1 tile1)
    stageA(0, 0, 0); stageB(0, 0, 0); stageB(0, 0, 1); stageA(0, 0, 1);
    stageA(1, 1, 0); stageB(1, 1, 0); stageB(1, 1, 1);
    asm volatile("s_waitcnt vmcnt(6)" ::: "memory");   // buf0 tile0 landed
    __builtin_amdgcn_s_barrier();
    __builtin_amdgcn_sched_barrier(0);

    for (int t = 0; t < NI; ++t) {
        const int kO1 = 2 * t + 1;                 // odd tile (buf1), valid
        const int kE2 = (2 * t + 2) & (NT - 1);    // next even (dummy-wraps at end)
        const int kO3 = (2 * t + 3) & (NT - 1);    // next odd

        // ph1: reads A(mh0),B(nh0) of buf0; stage Ah1(buf1, tile 2t+1)
        loadA(0, 0); loadB(0, 0, bv0);
        stageA(kO1, 1, 1);
        MIDSYNC();
        QUAD(0, bv0, 0);
        ENDBAR();

        // ph2: reads B(nh1) of buf0; stage Ah0(buf0, 2t+2)
        loadB(0, 1, bv1);
        stageA(kE2, 0, 0);
        MIDSYNC();
        QUAD(0, bv1, 1);
        ENDBAR();

        // ph3: reads A(mh1) of buf0; stage Bh0(buf0, 2t+2)
        loadA(0, 1);
        stageB(kE2, 0, 0);
        MIDSYNC();
        QUAD(1, bv0, 0);
        ENDBAR();

        // ph4: stage Bh1(buf0, 2t+2); counted vmcnt
        stageB(kE2, 0, 1);
        asm volatile("s_waitcnt vmcnt(6)" ::: "memory");
        MIDSYNC();
        QUAD(1, bv1, 1);
        ENDBAR();

        // ph5: reads A(mh0),B(nh0) of buf1; stage Ah1(buf0, 2t+2)
        loadA(1, 0); loadB(1, 0, bv0);
        stageA(kE2, 0, 1);
        MIDSYNC();
        QUAD(0, bv0, 0);
        ENDBAR();

        // ph6: reads B(nh1) of buf1; stage Ah0(buf1, 2t+3)
        loadB(1, 1, bv1);
        stageA(kO3, 1, 0);
        MIDSYNC();
        QUAD(0, bv1, 1);
        ENDBAR();

        // ph7: reads A(mh1) of buf1; stage Bh0(buf1, 2t+3)
        loadA(1, 1);
        stageB(kO3, 1, 0);
        MIDSYNC();
        QUAD(1, bv0, 0);
        ENDBAR();

        // ph8: stage Bh1(buf1, 2t+3); counted vmcnt
        stageB(kO3, 1, 1);
        asm volatile("s_waitcnt vmcnt(6)" ::: "memory");
        MIDSYNC();
        QUAD(1, bv1, 1);
        ENDBAR();
    }
    asm volatile("s_waitcnt vmcnt(0)" ::: "memory");   // drain dummy stages

    // epilogue: out[i][j] = 2*acc - xsq[i] - msq[j]
#pragma unroll
    for (int fm = 0; fm < 8; ++fm) {
        const int i0 = row0 + wr * 128 + fm * 16 + kq * 4;
        float xs[4];
#pragma unroll
        for (int r = 0; r < 4; ++r) xs[r] = xsq[i0 + r];
#pragma unroll
        for (int fn = 0; fn < 4; ++fn) {
            const int j = col0 + wc * 64 + fn * 16 + fr;
            if (j < CDIM) {
                const float ms = msq[j];
#pragma unroll
                for (int r = 0; r < 4; ++r)
                    out[(size_t)(i0 + r) * CDIM + j] =
                        2.0f * acc[fm][fn][r] - xs[r] - ms;
            }
        }
    }
}

// ---------------------------------------------------------------------------
extern "C" void kernel_launch(void* const* d_in, const int* in_sizes, int n_in,
                              void* d_out, int out_size, void* d_ws, size_t ws_size,
                              hipStream_t stream) {
    const float* x     = (const float*)d_in[0];   // [8192, 2048]
    const float* means = (const float*)d_in[1];   // [10000, 2048]
    float* out = (float*)d_out;                   // [8192, 10000]

    char* ws = (char*)d_ws;
    unsigned short* Xb = (unsigned short*)ws;                             // 8192*2048 bf16
    unsigned short* Mb = (unsigned short*)(ws + (size_t)BDIM * FDIM * 2); // 10240*2048 bf16
    float* xsq = (float*)(ws + (size_t)BDIM * FDIM * 2 + (size_t)CPAD * FDIM * 2);
    float* msq = xsq + BDIM;

    (void)hipFuncSetAttribute((const void*)nscm_gemm,
                              hipFuncAttributeMaxDynamicSharedMemorySize,
                              LDS_BYTES);

    convert_rows<<<BDIM, 256, 0, stream>>>(x, Xb, xsq, BDIM);
    convert_rows<<<CPAD, 256, 0, stream>>>(means, Mb, msq, CDIM);

    nscm_gemm<<<NWG, 512, LDS_BYTES, stream>>>(Xb, Mb, xsq, msq, out);
}

// Round 4
// 357.511 us; speedup vs baseline: 1.4012x; 1.0671x over previous
//
#include <hip/hip_runtime.h>
#include <hip/hip_bf16.h>
#include <stdint.h>

// Problem dims (fixed by the reference setup)
#define BDIM 8192      // rows of x
#define CDIM 10000     // class means
#define CPAD 10240     // 40 * 256
#define FDIM 2048      // feature dim (K)

#define BM 256
#define BN 256
#define BK 64
#define NT (FDIM / BK)          // 32 K-tiles
#define NI (NT / 2)             // 16 iterations (2 K-tiles each)
#define TM (BDIM / BM)          // 32
#define TN (CPAD / BN)          // 40
#define NWG (TM * TN)           // 1280, multiple of 8

#define HT_BYTES   16384        // one half-tile region (128 rows x 128 B)
#define DBUF_BYTES 65536        // A0|A1|B0|B1
#define LDS_BYTES  131072       // 2 dbuf slots

typedef __attribute__((ext_vector_type(8))) __bf16 bf16x8;
typedef __attribute__((ext_vector_type(4))) float  f32x4;

#define AS1 __attribute__((address_space(1)))
#define AS3 __attribute__((address_space(3)))

// ---------------------------------------------------------------------------
// Prep: f32 rows -> bf16 rows (RNE), plus per-row sum of squares in f32.
// ---------------------------------------------------------------------------
__global__ __launch_bounds__(256) void convert_rows(
    const float* __restrict__ src, unsigned short* __restrict__ dst,
    float* __restrict__ sq, int nvalid)
{
    const int row = blockIdx.x;
    const int tid = threadIdx.x;
    unsigned short* drow = dst + (size_t)row * FDIM;

    if (row >= nvalid) {
        uint4 z = make_uint4(0, 0, 0, 0);
        ((uint4*)drow)[tid] = z;
        if (tid == 0) sq[row] = 0.0f;
        return;
    }

    const float4* s = (const float4*)(src + (size_t)row * FDIM);
    float4 v0 = s[tid * 2 + 0];
    float4 v1 = s[tid * 2 + 1];

    float f[8] = {v0.x, v0.y, v0.z, v0.w, v1.x, v1.y, v1.z, v1.w};
    float ssum = 0.0f;
    union { unsigned short u[8]; uint4 v; } pk;
#pragma unroll
    for (int j = 0; j < 8; ++j) {
        ssum += f[j] * f[j];
        uint32_t b = __builtin_bit_cast(uint32_t, f[j]);
        b = b + 0x7fffu + ((b >> 16) & 1u);   // RNE to bf16
        pk.u[j] = (unsigned short)(b >> 16);
    }
    ((uint4*)drow)[tid] = pk.v;

#pragma unroll
    for (int off = 32; off > 0; off >>= 1)
        ssum += __shfl_down(ssum, off, 64);
    __shared__ float red[4];
    if ((tid & 63) == 0) red[tid >> 6] = ssum;
    __syncthreads();
    if (tid == 0) sq[row] = red[0] + red[1] + red[2] + red[3];
}

// ---------------------------------------------------------------------------
// 256x256 bf16 GEMM, 8-phase counted-vmcnt schedule (T1+T2+T3+T4+T5),
// fused epilogue: out[i][j] = 2*sum_k X[i][k]*M[j][k] - xsq[i] - msq[j]
//
// Tile mapping: each XCD owns a 4(tile_m) x 40(tile_n) slab, iterated as
// five 4x8 sub-rectangles so the ~32 co-resident blocks per XCD share
// 4 A-panels + 8 B-panels (co-moving K-slice working set ~1 MB << 4 MB L2).
// ---------------------------------------------------------------------------
#define MIDSYNC() do { \
    __builtin_amdgcn_s_barrier(); \
    asm volatile("s_waitcnt lgkmcnt(0)" ::: "memory"); \
    __builtin_amdgcn_sched_barrier(0); \
} while (0)

#define ENDBAR() do { \
    __builtin_amdgcn_s_barrier(); \
    __builtin_amdgcn_sched_barrier(0); \
} while (0)

// ks outermost: the two MFMAs accumulating into the same acc are 8 apart
#define QUAD(MH, BV, NH) do { \
    __builtin_amdgcn_s_setprio(1); \
    _Pragma("unroll") \
    for (int ks = 0; ks < 2; ++ks) \
      _Pragma("unroll") \
      for (int f = 0; f < 4; ++f) \
        _Pragma("unroll") \
        for (int f2 = 0; f2 < 2; ++f2) \
          acc[(MH)*4+f][(NH)*2+f2] = __builtin_amdgcn_mfma_f32_16x16x32_bf16( \
              av[f][ks], BV[f2][ks], acc[(MH)*4+f][(NH)*2+f2], 0, 0, 0); \
    __builtin_amdgcn_s_setprio(0); \
} while (0)

__global__ __launch_bounds__(512, 2) void nscm_gemm(
    const unsigned short* __restrict__ Xb, const unsigned short* __restrict__ Mb,
    const float* __restrict__ xsq, const float* __restrict__ msq,
    float* __restrict__ out)
{
    extern __shared__ char lds[];

    const int tid  = threadIdx.x;
    const int lane = tid & 63;
    const int wave = tid >> 6;       // 0..7
    const int wr = wave >> 2;        // 0..1  (M half)
    const int wc = wave & 3;         // 0..3  (N quarter)
    const int fr = lane & 15;
    const int kq = lane >> 4;        // 0..3

    // T1 + 2D clustering: xcd slab = 4 rows x 40 cols, five 4x8 sub-rects
    const int bid = blockIdx.x;
    const int xcd = bid & 7;
    const int c   = bid >> 3;            // 0..159 within XCD slab
    const int sub = c >> 5;              // 0..4   (column group of 8)
    const int tile_m = xcd * 4 + (c & 3);
    const int tile_n = sub * 8 + ((c >> 2) & 7);
    const int row0 = tile_m * BM;
    const int col0 = tile_n * BN;

    const int w8  = tid >> 3;                          // wave*8 + lane>>3
    const int sce = ((tid & 7) ^ (w8 & 7)) * 8;        // pre-swizzled src col (elems)
    const int xorv = (fr & 7) << 4;                    // T2 read-side XOR

    f32x4 acc[8][4] = {};
    bf16x8 av[4][2], bv0[2][2], bv1[2][2];

    // stage one A half-tile (h: rows with bit6==h) of K-tile kt into buf
    auto stageA = [&](int kt, int buf, int h) {
#pragma unroll
        for (int l = 0; l < 2; ++l) {
            const int w = l * 64 + w8;                           // 0..127 in-half
            const int grow = row0 + (w >> 6) * 128 + h * 64 + (w & 63);
            const unsigned short* src = Xb + (size_t)grow * FDIM + kt * BK + sce;
            char* dst = lds + buf * DBUF_BYTES + h * HT_BYTES
                        + (l * 64 + wave * 8) * 128;
            __builtin_amdgcn_global_load_lds((const AS1 void*)src,
                                             (AS3 void*)dst, 16, 0, 0);
        }
    };
    // stage one B half-tile (h: rows with bit5==h)
    auto stageB = [&](int kt, int buf, int h) {
#pragma unroll
        for (int l = 0; l < 2; ++l) {
            const int w = l * 64 + w8;
            const int grow = col0 + (w >> 5) * 64 + h * 32 + (w & 31);
            const unsigned short* src = Mb + (size_t)grow * FDIM + kt * BK + sce;
            char* dst = lds + buf * DBUF_BYTES + 32768 + h * HT_BYTES
                        + (l * 64 + wave * 8) * 128;
            __builtin_amdgcn_global_load_lds((const AS1 void*)src,
                                             (AS3 void*)dst, 16, 0, 0);
        }
    };

    auto loadA = [&](int buf, int mh) {
        const char* base = lds + buf * DBUF_BYTES + mh * HT_BYTES;
#pragma unroll
        for (int f = 0; f < 4; ++f) {
            const int w = wr * 64 + f * 16 + fr;
#pragma unroll
            for (int ks = 0; ks < 2; ++ks)
                av[f][ks] = *(const bf16x8*)(base + w * 128 +
                                             ((ks * 64 + kq * 16) ^ xorv));
        }
    };
    auto loadB = [&](int buf, int nh, bf16x8 (&bv)[2][2]) {
        const char* base = lds + buf * DBUF_BYTES + 32768 + nh * HT_BYTES;
#pragma unroll
        for (int f = 0; f < 2; ++f) {
            const int w = wc * 32 + f * 16 + fr;
#pragma unroll
            for (int ks = 0; ks < 2; ++ks)
                bv[f][ks] = *(const bf16x8*)(base + w * 128 +
                                             ((ks * 64 + kq * 16) ^ xorv));
        }
    };

    // prologue: 7 half-tiles (buf0 tile0 complete + 3/4 of buf1 tile1)
    stageA(0, 0, 0); stageB(0, 0, 0); stageB(0, 0, 1); stageA(0, 0, 1);
    stageA(1, 1, 0); stageB(1, 1, 0); stageB(1, 1, 1);
    asm volatile("s_waitcnt vmcnt(6)" ::: "memory");   // buf0 tile0 landed
    __builtin_amdgcn_s_barrier();
    __builtin_amdgcn_sched_barrier(0);

    for (int t = 0; t < NI; ++t) {
        const int kO1 = 2 * t + 1;                 // odd tile (buf1), valid
        const int kE2 = (2 * t + 2) & (NT - 1);    // next even (dummy-wraps at end)
        const int kO3 = (2 * t + 3) & (NT - 1);    // next odd

        // ph1: reads A(mh0),B(nh0) of buf0; stage Ah1(buf1, tile 2t+1)
        loadA(0, 0); loadB(0, 0, bv0);
        stageA(kO1, 1, 1);
        asm volatile("s_waitcnt lgkmcnt(8)" ::: "memory");  // pre-drain hint
        MIDSYNC();
        QUAD(0, bv0, 0);
        ENDBAR();

        // ph2: reads B(nh1) of buf0; stage Ah0(buf0, 2t+2)
        loadB(0, 1, bv1);
        stageA(kE2, 0, 0);
        MIDSYNC();
        QUAD(0, bv1, 1);
        ENDBAR();

        // ph3: reads A(mh1) of buf0; stage Bh0(buf0, 2t+2)
        loadA(0, 1);
        stageB(kE2, 0, 0);
        MIDSYNC();
        QUAD(1, bv0, 0);
        ENDBAR();

        // ph4: stage Bh1(buf0, 2t+2); counted vmcnt
        stageB(kE2, 0, 1);
        asm volatile("s_waitcnt vmcnt(6)" ::: "memory");
        MIDSYNC();
        QUAD(1, bv1, 1);
        ENDBAR();

        // ph5: reads A(mh0),B(nh0) of buf1; stage Ah1(buf0, 2t+2)
        loadA(1, 0); loadB(1, 0, bv0);
        stageA(kE2, 0, 1);
        asm volatile("s_waitcnt lgkmcnt(8)" ::: "memory");  // pre-drain hint
        MIDSYNC();
        QUAD(0, bv0, 0);
        ENDBAR();

        // ph6: reads B(nh1) of buf1; stage Ah0(buf1, 2t+3)
        loadB(1, 1, bv1);
        stageA(kO3, 1, 0);
        MIDSYNC();
        QUAD(0, bv1, 1);
        ENDBAR();

        // ph7: reads A(mh1) of buf1; stage Bh0(buf1, 2t+3)
        loadA(1, 1);
        stageB(kO3, 1, 0);
        MIDSYNC();
        QUAD(1, bv0, 0);
        ENDBAR();

        // ph8: stage Bh1(buf1, 2t+3); counted vmcnt
        stageB(kO3, 1, 1);
        asm volatile("s_waitcnt vmcnt(6)" ::: "memory");
        MIDSYNC();
        QUAD(1, bv1, 1);
        ENDBAR();
    }
    asm volatile("s_waitcnt vmcnt(0)" ::: "memory");   // drain dummy stages

    // epilogue: out[i][j] = 2*acc - xsq[i] - msq[j]
#pragma unroll
    for (int fm = 0; fm < 8; ++fm) {
        const int i0 = row0 + wr * 128 + fm * 16 + kq * 4;
        float xs[4];
#pragma unroll
        for (int r = 0; r < 4; ++r) xs[r] = xsq[i0 + r];
#pragma unroll
        for (int fn = 0; fn < 4; ++fn) {
            const int j = col0 + wc * 64 + fn * 16 + fr;
            if (j < CDIM) {
                const float ms = msq[j];
#pragma unroll
                for (int r = 0; r < 4; ++r)
                    out[(size_t)(i0 + r) * CDIM + j] =
                        2.0f * acc[fm][fn][r] - xs[r] - ms;
            }
        }
    }
}

// ---------------------------------------------------------------------------
extern "C" void kernel_launch(void* const* d_in, const int* in_sizes, int n_in,
                              void* d_out, int out_size, void* d_ws, size_t ws_size,
                              hipStream_t stream) {
    const float* x     = (const float*)d_in[0];   // [8192, 2048]
    const float* means = (const float*)d_in[1];   // [10000, 2048]
    float* out = (float*)d_out;                   // [8192, 10000]

    char* ws = (char*)d_ws;
    unsigned short* Xb = (unsigned short*)ws;                             // 8192*2048 bf16
    unsigned short* Mb = (unsigned short*)(ws + (size_t)BDIM * FDIM * 2); // 10240*2048 bf16
    float* xsq = (float*)(ws + (size_t)BDIM * FDIM * 2 + (size_t)CPAD * FDIM * 2);
    float* msq = xsq + BDIM;

    (void)hipFuncSetAttribute((const void*)nscm_gemm,
                              hipFuncAttributeMaxDynamicSharedMemorySize,
                              LDS_BYTES);

    convert_rows<<<BDIM, 256, 0, stream>>>(x, Xb, xsq, BDIM);
    convert_rows<<<CPAD, 256, 0, stream>>>(means, Mb, msq, CDIM);

    nscm_gemm<<<NWG, 512, LDS_BYTES, stream>>>(Xb, Mb, xsq, msq, out);
}

// Round 5
// 335.860 us; speedup vs baseline: 1.4915x; 1.0645x over previous
//
#include <hip/hip_runtime.h>
#include <hip/hip_bf16.h>
#include <stdint.h>

// Problem dims (fixed by the reference setup)
#define BDIM 8192      // rows of x
#define CDIM 10000     // class means
#define CPAD 10240     // 40 * 256
#define FDIM 2048      // feature dim (K)

#define BM 256
#define BN 256
#define BK 64
#define NT (FDIM / BK)          // 32 K-tiles
#define NI (NT / 2)             // 16 iterations (2 K-tiles each)
#define TM (BDIM / BM)          // 32
#define TN (CPAD / BN)          // 40
#define NWG (TM * TN)           // 1280, multiple of 8

#define HT_BYTES   16384        // one half-tile region (128 rows x 128 B)
#define DBUF_BYTES 65536        // A0|A1|B0|B1
#define EPI_WAVE_BYTES 17408    // 64 rows x 68 f32 (epilogue transpose tile)
#define LDS_BYTES  139264       // max(131072 main loop, 8*17408 epilogue)

typedef __attribute__((ext_vector_type(8))) __bf16 bf16x8;
typedef __attribute__((ext_vector_type(4))) float  f32x4;

#define AS1 __attribute__((address_space(1)))
#define AS3 __attribute__((address_space(3)))

// ---------------------------------------------------------------------------
// Prep (fused): f32 rows -> bf16 rows (RNE) + per-row sum of squares (f32).
// Blocks [0, BDIM) handle x; blocks [BDIM, BDIM+CPAD) handle means (padded).
// ---------------------------------------------------------------------------
__global__ __launch_bounds__(256) void convert_rows(
    const float* __restrict__ xsrc, const float* __restrict__ msrc,
    unsigned short* __restrict__ Xb, unsigned short* __restrict__ Mb,
    float* __restrict__ xsq, float* __restrict__ msq)
{
    const int b = blockIdx.x;
    const int tid = threadIdx.x;

    const float* src;
    unsigned short* drow;
    float* sq;
    int row;
    if (b < BDIM) {
        row = b; src = xsrc + (size_t)row * FDIM;
        drow = Xb + (size_t)row * FDIM; sq = xsq + row;
    } else {
        row = b - BDIM;
        drow = Mb + (size_t)row * FDIM; sq = msq + row;
        if (row >= CDIM) {
            ((uint4*)drow)[tid] = make_uint4(0, 0, 0, 0);
            if (tid == 0) *sq = 0.0f;
            return;
        }
        src = msrc + (size_t)row * FDIM;
    }

    const float4* s = (const float4*)src;
    float4 v0 = s[tid * 2 + 0];
    float4 v1 = s[tid * 2 + 1];

    float f[8] = {v0.x, v0.y, v0.z, v0.w, v1.x, v1.y, v1.z, v1.w};
    float ssum = 0.0f;
    union { unsigned short u[8]; uint4 v; } pk;
#pragma unroll
    for (int j = 0; j < 8; ++j) {
        ssum += f[j] * f[j];
        uint32_t bb = __builtin_bit_cast(uint32_t, f[j]);
        bb = bb + 0x7fffu + ((bb >> 16) & 1u);   // RNE to bf16
        pk.u[j] = (unsigned short)(bb >> 16);
    }
    ((uint4*)drow)[tid] = pk.v;

#pragma unroll
    for (int off = 32; off > 0; off >>= 1)
        ssum += __shfl_down(ssum, off, 64);
    __shared__ float red[4];
    if ((tid & 63) == 0) red[tid >> 6] = ssum;
    __syncthreads();
    if (tid == 0) *sq = red[0] + red[1] + red[2] + red[3];
}

// ---------------------------------------------------------------------------
// 256x256 bf16 GEMM, 8-phase counted-vmcnt schedule (T1+T2+T3+T4+T5),
// fused epilogue: out[i][j] = 2*sum_k X[i][k]*M[j][k] - xsq[i] - msq[j]
// Epilogue: per-wave LDS transpose -> float4 nontemporal stores.
// ---------------------------------------------------------------------------
#define MIDSYNC() do { \
    __builtin_amdgcn_s_barrier(); \
    asm volatile("s_waitcnt lgkmcnt(0)" ::: "memory"); \
    __builtin_amdgcn_sched_barrier(0); \
} while (0)

#define ENDBAR() do { \
    __builtin_amdgcn_s_barrier(); \
    __builtin_amdgcn_sched_barrier(0); \
} while (0)

// ks outermost: the two MFMAs accumulating into the same acc are 8 apart
#define QUAD(MH, BV, NH) do { \
    __builtin_amdgcn_s_setprio(1); \
    _Pragma("unroll") \
    for (int ks = 0; ks < 2; ++ks) \
      _Pragma("unroll") \
      for (int f = 0; f < 4; ++f) \
        _Pragma("unroll") \
        for (int f2 = 0; f2 < 2; ++f2) \
          acc[(MH)*4+f][(NH)*2+f2] = __builtin_amdgcn_mfma_f32_16x16x32_bf16( \
              av[f][ks], BV[f2][ks], acc[(MH)*4+f][(NH)*2+f2], 0, 0, 0); \
    __builtin_amdgcn_s_setprio(0); \
} while (0)

__global__ __launch_bounds__(512, 2) void nscm_gemm(
    const unsigned short* __restrict__ Xb, const unsigned short* __restrict__ Mb,
    const float* __restrict__ xsq, const float* __restrict__ msq,
    float* __restrict__ out)
{
    extern __shared__ char lds[];

    const int tid  = threadIdx.x;
    const int lane = tid & 63;
    const int wave = tid >> 6;       // 0..7
    const int wr = wave >> 2;        // 0..1  (M half)
    const int wc = wave & 3;         // 0..3  (N quarter)
    const int fr = lane & 15;
    const int kq = lane >> 4;        // 0..3

    // T1 + 2D clustering: xcd slab = 4 rows x 40 cols, five 4x8 sub-rects
    const int bid = blockIdx.x;
    const int xcd = bid & 7;
    const int c   = bid >> 3;            // 0..159 within XCD slab
    const int sub = c >> 5;              // 0..4   (column group of 8)
    const int tile_m = xcd * 4 + (c & 3);
    const int tile_n = sub * 8 + ((c >> 2) & 7);
    const int row0 = tile_m * BM;
    const int col0 = tile_n * BN;

    const int w8  = tid >> 3;                          // wave*8 + lane>>3
    const int sce = ((tid & 7) ^ (w8 & 7)) * 8;        // pre-swizzled src col (elems)
    const int xorv = (fr & 7) << 4;                    // T2 read-side XOR

    f32x4 acc[8][4] = {};
    bf16x8 av[4][2], bv0[2][2], bv1[2][2];

    // stage one A half-tile (h: rows with bit6==h) of K-tile kt into buf
    auto stageA = [&](int kt, int buf, int h) {
#pragma unroll
        for (int l = 0; l < 2; ++l) {
            const int w = l * 64 + w8;                           // 0..127 in-half
            const int grow = row0 + (w >> 6) * 128 + h * 64 + (w & 63);
            const unsigned short* src = Xb + (size_t)grow * FDIM + kt * BK + sce;
            char* dst = lds + buf * DBUF_BYTES + h * HT_BYTES
                        + (l * 64 + wave * 8) * 128;
            __builtin_amdgcn_global_load_lds((const AS1 void*)src,
                                             (AS3 void*)dst, 16, 0, 0);
        }
    };
    // stage one B half-tile (h: rows with bit5==h)
    auto stageB = [&](int kt, int buf, int h) {
#pragma unroll
        for (int l = 0; l < 2; ++l) {
            const int w = l * 64 + w8;
            const int grow = col0 + (w >> 5) * 64 + h * 32 + (w & 31);
            const unsigned short* src = Mb + (size_t)grow * FDIM + kt * BK + sce;
            char* dst = lds + buf * DBUF_BYTES + 32768 + h * HT_BYTES
                        + (l * 64 + wave * 8) * 128;
            __builtin_amdgcn_global_load_lds((const AS1 void*)src,
                                             (AS3 void*)dst, 16, 0, 0);
        }
    };

    auto loadA = [&](int buf, int mh) {
        const char* base = lds + buf * DBUF_BYTES + mh * HT_BYTES;
#pragma unroll
        for (int f = 0; f < 4; ++f) {
            const int w = wr * 64 + f * 16 + fr;
#pragma unroll
            for (int ks = 0; ks < 2; ++ks)
                av[f][ks] = *(const bf16x8*)(base + w * 128 +
                                             ((ks * 64 + kq * 16) ^ xorv));
        }
    };
    auto loadB = [&](int buf, int nh, bf16x8 (&bv)[2][2]) {
        const char* base = lds + buf * DBUF_BYTES + 32768 + nh * HT_BYTES;
#pragma unroll
        for (int f = 0; f < 2; ++f) {
            const int w = wc * 32 + f * 16 + fr;
#pragma unroll
            for (int ks = 0; ks < 2; ++ks)
                bv[f][ks] = *(const bf16x8*)(base + w * 128 +
                                             ((ks * 64 + kq * 16) ^ xorv));
        }
    };

    // prologue: 7 half-tiles (buf0 tile0 complete + 3/4 of buf1 tile1)
    stageA(0, 0, 0); stageB(0, 0, 0); stageB(0, 0, 1); stageA(0, 0, 1);
    stageA(1, 1, 0); stageB(1, 1, 0); stageB(1, 1, 1);
    asm volatile("s_waitcnt vmcnt(6)" ::: "memory");   // buf0 tile0 landed
    __builtin_amdgcn_s_barrier();
    __builtin_amdgcn_sched_barrier(0);

    for (int t = 0; t < NI; ++t) {
        const int kO1 = 2 * t + 1;                 // odd tile (buf1), valid
        const int kE2 = (2 * t + 2) & (NT - 1);    // next even (dummy-wraps at end)
        const int kO3 = (2 * t + 3) & (NT - 1);    // next odd

        // ph1: reads A(mh0),B(nh0) of buf0; stage Ah1(buf1, tile 2t+1)
        loadA(0, 0); loadB(0, 0, bv0);
        stageA(kO1, 1, 1);
        asm volatile("s_waitcnt lgkmcnt(8)" ::: "memory");
        MIDSYNC();
        QUAD(0, bv0, 0);
        ENDBAR();

        // ph2: reads B(nh1) of buf0; stage Ah0(buf0, 2t+2)
        loadB(0, 1, bv1);
        stageA(kE2, 0, 0);
        MIDSYNC();
        QUAD(0, bv1, 1);
        ENDBAR();

        // ph3: reads A(mh1) of buf0; stage Bh0(buf0, 2t+2)
        loadA(0, 1);
        stageB(kE2, 0, 0);
        MIDSYNC();
        QUAD(1, bv0, 0);
        ENDBAR();

        // ph4: stage Bh1(buf0, 2t+2); counted vmcnt
        stageB(kE2, 0, 1);
        asm volatile("s_waitcnt vmcnt(6)" ::: "memory");
        MIDSYNC();
        QUAD(1, bv1, 1);
        ENDBAR();

        // ph5: reads A(mh0),B(nh0) of buf1; stage Ah1(buf0, 2t+2)
        loadA(1, 0); loadB(1, 0, bv0);
        stageA(kE2, 0, 1);
        asm volatile("s_waitcnt lgkmcnt(8)" ::: "memory");
        MIDSYNC();
        QUAD(0, bv0, 0);
        ENDBAR();

        // ph6: reads B(nh1) of buf1; stage Ah0(buf1, 2t+3)
        loadB(1, 1, bv1);
        stageA(kO3, 1, 0);
        MIDSYNC();
        QUAD(0, bv1, 1);
        ENDBAR();

        // ph7: reads A(mh1) of buf1; stage Bh0(buf1, 2t+3)
        loadA(1, 1);
        stageB(kO3, 1, 0);
        MIDSYNC();
        QUAD(1, bv0, 0);
        ENDBAR();

        // ph8: stage Bh1(buf1, 2t+3); counted vmcnt
        stageB(kO3, 1, 1);
        asm volatile("s_waitcnt vmcnt(6)" ::: "memory");
        MIDSYNC();
        QUAD(1, bv1, 1);
        ENDBAR();
    }

    // drain dummy stages (they write LDS) and sync before epilogue reuses LDS
    asm volatile("s_waitcnt vmcnt(0)" ::: "memory");
    __builtin_amdgcn_s_barrier();
    __builtin_amdgcn_sched_barrier(0);

    // ---- epilogue: per-wave LDS transpose -> coalesced float4 nt stores ----
    // out[i][j] = 2*acc - xsq[i] - msq[j]
    float* wtile = (float*)(lds + wave * EPI_WAVE_BYTES);  // [64][68] f32
    const int rr = lane >> 4;              // 0..3 (row within 4-row pass)
    const int cq = lane & 15;              // col-quad index
    const int gc = col0 + wc * 64 + cq * 4;
    float ms0 = 0.f, ms1 = 0.f, ms2 = 0.f, ms3 = 0.f;
    if (gc < CDIM) {
        ms0 = msq[gc]; ms1 = msq[gc + 1]; ms2 = msq[gc + 2]; ms3 = msq[gc + 3];
    }

#pragma unroll
    for (int mh = 0; mh < 2; ++mh) {
        // scatter acc fragments into the wave's LDS tile (row-major, pad 68)
#pragma unroll
        for (int f = 0; f < 4; ++f)
#pragma unroll
            for (int fn = 0; fn < 4; ++fn) {
                const int lr = f * 16 + kq * 4;
                const int lc = fn * 16 + fr;
#pragma unroll
                for (int r = 0; r < 4; ++r)
                    wtile[(lr + r) * 68 + lc] = acc[mh * 4 + f][fn][r];
            }
        asm volatile("s_waitcnt lgkmcnt(0)" ::: "memory");
        __builtin_amdgcn_sched_barrier(0);

        if (gc < CDIM) {
#pragma unroll
            for (int i = 0; i < 16; ++i) {
                const int row = i * 4 + rr;
                f32x4 v = *(const f32x4*)&wtile[row * 68 + cq * 4];
                const int gr = row0 + wr * 128 + mh * 64 + row;
                const float xsv = xsq[gr];
                f32x4 o;
                o[0] = 2.0f * v[0] - xsv - ms0;
                o[1] = 2.0f * v[1] - xsv - ms1;
                o[2] = 2.0f * v[2] - xsv - ms2;
                o[3] = 2.0f * v[3] - xsv - ms3;
                __builtin_nontemporal_store(
                    o, (f32x4*)(out + (size_t)gr * CDIM + gc));
            }
        }
        // wave-local reuse of wtile in next mh: ensure reads retired
        asm volatile("s_waitcnt lgkmcnt(0)" ::: "memory");
        __builtin_amdgcn_sched_barrier(0);
    }
}

// ---------------------------------------------------------------------------
extern "C" void kernel_launch(void* const* d_in, const int* in_sizes, int n_in,
                              void* d_out, int out_size, void* d_ws, size_t ws_size,
                              hipStream_t stream) {
    const float* x     = (const float*)d_in[0];   // [8192, 2048]
    const float* means = (const float*)d_in[1];   // [10000, 2048]
    float* out = (float*)d_out;                   // [8192, 10000]

    char* ws = (char*)d_ws;
    unsigned short* Xb = (unsigned short*)ws;                             // 8192*2048 bf16
    unsigned short* Mb = (unsigned short*)(ws + (size_t)BDIM * FDIM * 2); // 10240*2048 bf16
    float* xsq = (float*)(ws + (size_t)BDIM * FDIM * 2 + (size_t)CPAD * FDIM * 2);
    float* msq = xsq + BDIM;

    (void)hipFuncSetAttribute((const void*)nscm_gemm,
                              hipFuncAttributeMaxDynamicSharedMemorySize,
                              LDS_BYTES);

    convert_rows<<<BDIM + CPAD, 256, 0, stream>>>(x, means, Xb, Mb, xsq, msq);

    nscm_gemm<<<NWG, 512, LDS_BYTES, stream>>>(Xb, Mb, xsq, msq, out);
}